// Round 1
// baseline (458.474 us; speedup 1.0000x reference)
//
#include <hip/hip_runtime.h>
#include <hip/hip_bf16.h>
#include <stdint.h>

// Problem constants (from setup_inputs; fixed for this bench)
#define N_B   2
#define L_DIM 4800
#define S_DIM 4800
#define C_DIM 256
#define H0 60
#define W0 80
#define H1 60
#define W1 80
#define BORDER 2
#define THR 0.01f
#define SIM_SCALE 0.0390625f   // 1/(C*TEMP) = 1/25.6

typedef __attribute__((ext_vector_type(8))) short bf16x8;
typedef __attribute__((ext_vector_type(4))) float f32x4;

// Workspace layout (bytes)
#define OFF_A  0                      // 2*4800*256*2 = 4,915,200  (bf16 A)
#define OFF_B  4915200                // 4,915,200                 (bf16 B)
#define OFF_RS 9830400                // 9600 f32 rowsum
#define OFF_CS 9868800                // 9600 f32 colsum
#define OFF_CM 9907200                // 9600 u32 colmax bits
#define OFF_RA 9945600                // 9600 u64 packed row argmax
#define ZERO_BYTES 192000             // OFF_RS..end

__device__ __forceinline__ unsigned short f2bf_rne(float x) {
    unsigned int u = __float_as_uint(x);
    unsigned int r = (u + 0x7fffu + ((u >> 16) & 1u)) >> 16;
    return (unsigned short)r;
}

// ---- K0: fp32 -> bf16 conversion of both feature tensors -------------------
__global__ __launch_bounds__(256)
void convert_kernel(const float* __restrict__ f0, const float* __restrict__ f1,
                    unsigned short* __restrict__ a, unsigned short* __restrict__ b) {
    int idx = blockIdx.x * 256 + threadIdx.x;
    int i = idx * 4;                         // 614400 threads * 4 = 2,457,600 exact
    float4 va = *reinterpret_cast<const float4*>(f0 + i);
    float4 vb = *reinterpret_cast<const float4*>(f1 + i);
    ushort4 ha, hb;
    ha.x = f2bf_rne(va.x); ha.y = f2bf_rne(va.y); ha.z = f2bf_rne(va.z); ha.w = f2bf_rne(va.w);
    hb.x = f2bf_rne(vb.x); hb.y = f2bf_rne(vb.y); hb.z = f2bf_rne(vb.z); hb.w = f2bf_rne(vb.w);
    *reinterpret_cast<ushort4*>(a + i) = ha;
    *reinterpret_cast<ushort4*>(b + i) = hb;
}

// ---- K1/K2: 96x96-tile bf16 MFMA GEMM, two passes --------------------------
// Pass 1: accumulate rowsum/colsum of exp(sim).
// Pass 2: conf = exp(sim)^2/(rowsum*colsum); write conf; track row argmax (packed)
//         and col max via atomics.
template <int PASS>
__global__ __launch_bounds__(256)
void gemm_pass(const unsigned short* __restrict__ A,
               const unsigned short* __restrict__ B,
               float* __restrict__ rowsum, float* __restrict__ colsum,
               unsigned long long* __restrict__ rowarg,
               unsigned int* __restrict__ colmaxbits,
               float* __restrict__ conf_out) {
    const int n      = blockIdx.z;
    const int tile_r = blockIdx.y * 96;
    const int tile_c = blockIdx.x * 96;
    const int lane   = threadIdx.x & 63;
    const int w      = threadIdx.x >> 6;     // 4 waves, 2x2 wave grid
    const int wr     = w >> 1, wc = w & 1;
    const int base_r = tile_r + wr * 48;
    const int base_c = tile_c + wc * 48;
    const int lrow   = lane & 15;            // fragment row (A) / col (B)
    const int kgrp   = lane >> 4;            // k-chunk selector

    const unsigned short* Abase = A + (size_t)n * L_DIM * C_DIM;
    const unsigned short* Bbase = B + (size_t)n * S_DIM * C_DIM;

    f32x4 acc[3][3] = {};

    #pragma unroll
    for (int kk = 0; kk < 8; ++kk) {
        const int k0 = kk * 32 + kgrp * 8;
        bf16x8 af[3], bf[3];
        #pragma unroll
        for (int f = 0; f < 3; ++f) {
            af[f] = *reinterpret_cast<const bf16x8*>(
                Abase + (size_t)(base_r + f * 16 + lrow) * C_DIM + k0);
            bf[f] = *reinterpret_cast<const bf16x8*>(
                Bbase + (size_t)(base_c + f * 16 + lrow) * C_DIM + k0);
        }
        #pragma unroll
        for (int i = 0; i < 3; ++i)
            #pragma unroll
            for (int j = 0; j < 3; ++j)
                acc[i][j] = __builtin_amdgcn_mfma_f32_16x16x32_bf16(af[i], bf[j], acc[i][j], 0, 0, 0);
    }

    // C/D layout: col = base_c + j*16 + lrow ; row = base_r + i*16 + kgrp*4 + q
    if (PASS == 1) {
        float rsum[3][4];
        float csum[3];
        #pragma unroll
        for (int i = 0; i < 3; ++i)
            #pragma unroll
            for (int q = 0; q < 4; ++q) rsum[i][q] = 0.f;
        #pragma unroll
        for (int j = 0; j < 3; ++j) csum[j] = 0.f;

        #pragma unroll
        for (int i = 0; i < 3; ++i)
            #pragma unroll
            for (int j = 0; j < 3; ++j)
                #pragma unroll
                for (int q = 0; q < 4; ++q) {
                    float e = __expf(acc[i][j][q] * SIM_SCALE);
                    rsum[i][q] += e;
                    csum[j]    += e;
                }

        // sum across the 16 lanes that share rows (bits 0..3 of lane)
        #pragma unroll
        for (int m = 1; m < 16; m <<= 1)
            #pragma unroll
            for (int i = 0; i < 3; ++i)
                #pragma unroll
                for (int q = 0; q < 4; ++q)
                    rsum[i][q] += __shfl_xor(rsum[i][q], m, 64);
        if (lrow == 0) {
            #pragma unroll
            for (int i = 0; i < 3; ++i)
                #pragma unroll
                for (int q = 0; q < 4; ++q)
                    atomicAdd(&rowsum[(size_t)n * L_DIM + base_r + i * 16 + kgrp * 4 + q],
                              rsum[i][q]);
        }
        // sum across the 4 lane-groups that share cols (bits 4..5 of lane)
        #pragma unroll
        for (int m = 16; m < 64; m <<= 1)
            #pragma unroll
            for (int j = 0; j < 3; ++j)
                csum[j] += __shfl_xor(csum[j], m, 64);
        if (kgrp == 0) {
            #pragma unroll
            for (int j = 0; j < 3; ++j)
                atomicAdd(&colsum[(size_t)n * S_DIM + base_c + j * 16 + lrow], csum[j]);
        }
    } else {
        float irs[3][4];
        #pragma unroll
        for (int i = 0; i < 3; ++i)
            #pragma unroll
            for (int q = 0; q < 4; ++q)
                irs[i][q] = 1.0f / rowsum[(size_t)n * L_DIM + base_r + i * 16 + kgrp * 4 + q];
        float ics[3];
        #pragma unroll
        for (int j = 0; j < 3; ++j)
            ics[j] = 1.0f / colsum[(size_t)n * S_DIM + base_c + j * 16 + lrow];

        unsigned long long rmax[3][4];
        #pragma unroll
        for (int i = 0; i < 3; ++i)
            #pragma unroll
            for (int q = 0; q < 4; ++q) rmax[i][q] = 0ull;
        float cmax[3] = {0.f, 0.f, 0.f};

        #pragma unroll
        for (int i = 0; i < 3; ++i)
            #pragma unroll
            for (int j = 0; j < 3; ++j)
                #pragma unroll
                for (int q = 0; q < 4; ++q) {
                    float e    = __expf(acc[i][j][q] * SIM_SCALE);
                    float conf = (e * e) * irs[i][q] * ics[j];
                    int row = base_r + i * 16 + kgrp * 4 + q;
                    int col = base_c + j * 16 + lrow;
                    conf_out[((size_t)n * L_DIM + row) * S_DIM + col] = conf;
                    unsigned long long p =
                        ((unsigned long long)__float_as_uint(conf) << 32) | (unsigned)col;
                    if (p > rmax[i][q]) rmax[i][q] = p;
                    if (conf > cmax[j]) cmax[j] = conf;
                }

        // row packed-max across the 16 lanes sharing rows
        #pragma unroll
        for (int m = 1; m < 16; m <<= 1)
            #pragma unroll
            for (int i = 0; i < 3; ++i)
                #pragma unroll
                for (int q = 0; q < 4; ++q) {
                    unsigned long long o = __shfl_xor(rmax[i][q], m, 64);
                    if (o > rmax[i][q]) rmax[i][q] = o;
                }
        if (lrow == 0) {
            #pragma unroll
            for (int i = 0; i < 3; ++i)
                #pragma unroll
                for (int q = 0; q < 4; ++q)
                    atomicMax(&rowarg[(size_t)n * L_DIM + base_r + i * 16 + kgrp * 4 + q],
                              rmax[i][q]);
        }
        // col max across the 4 lane-groups sharing cols
        #pragma unroll
        for (int m = 16; m < 64; m <<= 1)
            #pragma unroll
            for (int j = 0; j < 3; ++j) {
                float o = __shfl_xor(cmax[j], m, 64);
                if (o > cmax[j]) cmax[j] = o;
            }
        if (kgrp == 0) {
            #pragma unroll
            for (int j = 0; j < 3; ++j)
                atomicMax(&colmaxbits[(size_t)n * S_DIM + base_c + j * 16 + lrow],
                          __float_as_uint(cmax[j]));
        }
    }
}

// ---- K3: match extraction ---------------------------------------------------
__global__ __launch_bounds__(256)
void finalize_kernel(const unsigned long long* __restrict__ rowarg,
                     const unsigned int* __restrict__ colmaxbits,
                     float* __restrict__ out_maskv,
                     float* __restrict__ out_allj,
                     float* __restrict__ out_mconf) {
    int idx = blockIdx.x * 256 + threadIdx.x;
    if (idx >= N_B * L_DIM) return;
    int n = idx / L_DIM;
    int l = idx - n * L_DIM;
    unsigned long long p = rowarg[idx];
    unsigned int cbits = (unsigned int)(p >> 32);
    int s = (int)(p & 0xffffffffu);
    float cv = __uint_as_float(cbits);
    int i0 = l / W0, j0 = l - i0 * W0;
    int i1 = s / W1, j1 = s - i1 * W1;
    bool border = (i0 >= BORDER) && (i0 < H0 - BORDER) &&
                  (j0 >= BORDER) && (j0 < W0 - BORDER) &&
                  (i1 >= BORDER) && (i1 < H1 - BORDER) &&
                  (j1 >= BORDER) && (j1 < W1 - BORDER);
    bool matched = (cv > THR) && border && (colmaxbits[n * S_DIM + s] == cbits);
    out_maskv[idx] = matched ? 1.0f : 0.0f;
    out_allj[idx]  = matched ? (float)s : 0.0f;
    out_mconf[idx] = matched ? cv : 0.0f;
}

extern "C" void kernel_launch(void* const* d_in, const int* in_sizes, int n_in,
                              void* d_out, int out_size, void* d_ws, size_t ws_size,
                              hipStream_t stream) {
    const float* f0 = (const float*)d_in[0];
    const float* f1 = (const float*)d_in[1];
    float* out = (float*)d_out;

    char* ws = (char*)d_ws;
    unsigned short*     Abf        = (unsigned short*)(ws + OFF_A);
    unsigned short*     Bbf        = (unsigned short*)(ws + OFF_B);
    float*              rowsum     = (float*)(ws + OFF_RS);
    float*              colsum     = (float*)(ws + OFF_CS);
    unsigned int*       colmaxbits = (unsigned int*)(ws + OFF_CM);
    unsigned long long* rowarg     = (unsigned long long*)(ws + OFF_RA);

    // zero the reduction accumulators (ws is poisoned 0xAA before every call)
    hipMemsetAsync(ws + OFF_RS, 0, ZERO_BYTES, stream);

    // K0: convert both feature tensors to bf16
    convert_kernel<<<2400, 256, 0, stream>>>(f0, f1, Abf, Bbf);

    dim3 grid(S_DIM / 96, L_DIM / 96, N_B);   // 50 x 50 x 2
    gemm_pass<1><<<grid, 256, 0, stream>>>(Abf, Bbf, rowsum, colsum,
                                           nullptr, nullptr, nullptr);
    gemm_pass<2><<<grid, 256, 0, stream>>>(Abf, Bbf, rowsum, colsum,
                                           rowarg, colmaxbits, out);

    const size_t CONF_ELEMS = (size_t)N_B * L_DIM * S_DIM;  // 46,080,000
    float* out_maskv = out + CONF_ELEMS;
    float* out_allj  = out_maskv + (size_t)N_B * L_DIM;
    float* out_mconf = out_allj  + (size_t)N_B * L_DIM;
    finalize_kernel<<<(N_B * L_DIM + 255) / 256, 256, 0, stream>>>(
        rowarg, colmaxbits, out_maskv, out_allj, out_mconf);
}

// Round 2
// 386.305 us; speedup vs baseline: 1.1868x; 1.1868x over previous
//
#include <hip/hip_runtime.h>
#include <hip/hip_bf16.h>
#include <stdint.h>

// Problem constants (fixed for this bench)
#define N_B   2
#define L_DIM 4800
#define S_DIM 4800
#define C_DIM 256
#define H0 60
#define W0 80
#define H1 60
#define W1 80
#define BORDER 2
#define THR 0.01f
#define SIM_SCALE 0.0390625f   // 1/(C*TEMP) = 1/25.6

// GEMM tiling
#define TILE 192               // 4800/192 = 25 tiles per dim
#define BK   32
#define NK   8                 // 256/32
#define A_BYTES 12288          // 192*32*2
#define PH_BYTES 24576         // A tile + B tile per phase
#define CHUNKS_AB 1536         // (192*4)*2 16B chunks per phase

typedef __attribute__((ext_vector_type(8))) short bf16x8;
typedef __attribute__((ext_vector_type(4))) float f32x4;

// Workspace layout (bytes)
#define OFF_A  0                      // bf16 A: 4,915,200
#define OFF_B  4915200                // bf16 B: 4,915,200
#define OFF_RS 9830400                // 9600 f32 rowsum
#define OFF_CS 9868800                // 9600 f32 colsum
#define OFF_CM 9907200                // 9600 u32 colmax bits
#define OFF_RA 9945600                // 9600 u64 packed row argmax
#define ZERO_BYTES 192000

__device__ __forceinline__ unsigned short f2bf_rne(float x) {
    unsigned int u = __float_as_uint(x);
    unsigned int r = (u + 0x7fffu + ((u >> 16) & 1u)) >> 16;
    return (unsigned short)r;
}

__device__ __forceinline__ void gload16(const void* g, void* l) {
    __builtin_amdgcn_global_load_lds(
        (const __attribute__((address_space(1))) void*)g,
        (__attribute__((address_space(3))) void*)l, 16, 0, 0);
}

// ---- K0: fp32 -> bf16 conversion -------------------------------------------
__global__ __launch_bounds__(256)
void convert_kernel(const float* __restrict__ f0, const float* __restrict__ f1,
                    unsigned short* __restrict__ a, unsigned short* __restrict__ b) {
    int idx = blockIdx.x * 256 + threadIdx.x;
    int i = idx * 4;
    float4 va = *reinterpret_cast<const float4*>(f0 + i);
    float4 vb = *reinterpret_cast<const float4*>(f1 + i);
    ushort4 ha, hb;
    ha.x = f2bf_rne(va.x); ha.y = f2bf_rne(va.y); ha.z = f2bf_rne(va.z); ha.w = f2bf_rne(va.w);
    hb.x = f2bf_rne(vb.x); hb.y = f2bf_rne(vb.y); hb.z = f2bf_rne(vb.z); hb.w = f2bf_rne(vb.w);
    *reinterpret_cast<ushort4*>(a + i) = ha;
    *reinterpret_cast<ushort4*>(b + i) = hb;
}

// ---- K1/K2: 192x192-tile bf16 MFMA GEMM, LDS-staged, two passes ------------
template <int PASS>
__global__ __launch_bounds__(512)
void gemm_pass(const unsigned short* __restrict__ A,
               const unsigned short* __restrict__ B,
               float* __restrict__ rowsum, float* __restrict__ colsum,
               unsigned long long* __restrict__ rowarg,
               unsigned int* __restrict__ colmaxbits,
               float* __restrict__ conf_out) {
    __shared__ char smem[2 * PH_BYTES];   // 48 KB double-buffered A+B tiles

    const int n      = blockIdx.z;
    const int tile_r = blockIdx.y * TILE;
    const int tile_c = blockIdx.x * TILE;
    const int tid    = threadIdx.x;
    const int lane   = tid & 63;
    const int w      = tid >> 6;          // 8 waves: 2 (row) x 4 (col)
    const int wr     = w >> 2;
    const int wc     = w & 3;
    const int lrow   = lane & 15;
    const int kgrp   = lane >> 4;

    const unsigned short* Abase = A + (size_t)n * L_DIM * C_DIM + (size_t)tile_r * C_DIM;
    const unsigned short* Bbase = B + (size_t)n * S_DIM * C_DIM + (size_t)tile_c * C_DIM;

    f32x4 acc[6][3] = {};

    // ---- staging: 1536 16B chunks/phase; chunk ci of tensor = row*4 + kc ----
    // LDS layout: A at [0,12288): byte (row*4+kc)*16 ; B same at +12288.
    // Wave-uniform LDS base + lane*16 (chunk idx linear in tid) — gload_lds safe.
#define STAGE(PH, KK)                                                          \
    {                                                                          \
        const int kbase = (KK) * BK;                                           \
        _Pragma("unroll")                                                      \
        for (int r = 0; r < 3; ++r) {                                          \
            int idx = r * 512 + tid;                                           \
            int ci  = (idx < 768) ? idx : idx - 768;                           \
            int row = ci >> 2;                                                 \
            int kc  = ci & 3;                                                  \
            const unsigned short* src =                                        \
                ((idx < 768) ? Abase : Bbase) + (size_t)row * C_DIM + kbase + kc * 8; \
            gload16(src, smem + (PH) * PH_BYTES + idx * 16);                   \
        }                                                                      \
    }

    STAGE(0, 0)
    #pragma unroll
    for (int kk = 0; kk < NK; ++kk) {
        __syncthreads();                  // drains vmcnt (staged data visible)
        const int phase = kk & 1;
        if (kk + 1 < NK) STAGE(phase ^ 1, kk + 1)

        const char* pa = smem + phase * PH_BYTES;
        bf16x8 af[6], bb[3];
        #pragma unroll
        for (int i = 0; i < 6; ++i)
            af[i] = *reinterpret_cast<const bf16x8*>(
                pa + ((wr * 96 + i * 16 + lrow) * 4 + kgrp) * 16);
        #pragma unroll
        for (int j = 0; j < 3; ++j)
            bb[j] = *reinterpret_cast<const bf16x8*>(
                pa + A_BYTES + ((wc * 48 + j * 16 + lrow) * 4 + kgrp) * 16);
        #pragma unroll
        for (int i = 0; i < 6; ++i)
            #pragma unroll
            for (int j = 0; j < 3; ++j)
                acc[i][j] = __builtin_amdgcn_mfma_f32_16x16x32_bf16(
                    af[i], bb[j], acc[i][j], 0, 0, 0);
    }
#undef STAGE

    // C/D layout: row = tile_r + wr*96 + i*16 + kgrp*4 + q
    //             col = tile_c + wc*48 + j*16 + lrow
    if (PASS == 1) {
        float rs[6][4] = {};
        float cs[3]    = {};
        #pragma unroll
        for (int i = 0; i < 6; ++i)
            #pragma unroll
            for (int j = 0; j < 3; ++j)
                #pragma unroll
                for (int q = 0; q < 4; ++q) {
                    float e = __expf(acc[i][j][q] * SIM_SCALE);
                    rs[i][q] += e;
                    cs[j]    += e;
                }
        #pragma unroll
        for (int m = 1; m < 16; m <<= 1)
            #pragma unroll
            for (int i = 0; i < 6; ++i)
                #pragma unroll
                for (int q = 0; q < 4; ++q)
                    rs[i][q] += __shfl_xor(rs[i][q], m, 64);
        if (lrow == 0) {
            #pragma unroll
            for (int i = 0; i < 6; ++i)
                #pragma unroll
                for (int q = 0; q < 4; ++q)
                    atomicAdd(&rowsum[(size_t)n * L_DIM + tile_r + wr * 96 + i * 16 + kgrp * 4 + q],
                              rs[i][q]);
        }
        #pragma unroll
        for (int m = 16; m < 64; m <<= 1)
            #pragma unroll
            for (int j = 0; j < 3; ++j)
                cs[j] += __shfl_xor(cs[j], m, 64);
        if (kgrp == 0) {
            #pragma unroll
            for (int j = 0; j < 3; ++j)
                atomicAdd(&colsum[(size_t)n * S_DIM + tile_c + wc * 48 + j * 16 + lrow], cs[j]);
        }
    } else {
        float irs[6][4];
        #pragma unroll
        for (int i = 0; i < 6; ++i)
            #pragma unroll
            for (int q = 0; q < 4; ++q)
                irs[i][q] = 1.0f /
                    rowsum[(size_t)n * L_DIM + tile_r + wr * 96 + i * 16 + kgrp * 4 + q];
        float ics[3];
        #pragma unroll
        for (int j = 0; j < 3; ++j)
            ics[j] = 1.0f / colsum[(size_t)n * S_DIM + tile_c + wc * 48 + j * 16 + lrow];

        unsigned long long rmax[6][4] = {};
        float cmax[3] = {};

        #pragma unroll
        for (int i = 0; i < 6; ++i)
            #pragma unroll
            for (int j = 0; j < 3; ++j)
                #pragma unroll
                for (int q = 0; q < 4; ++q) {
                    float e    = __expf(acc[i][j][q] * SIM_SCALE);
                    float conf = (e * e) * irs[i][q] * ics[j];
                    int row = tile_r + wr * 96 + i * 16 + kgrp * 4 + q;
                    int col = tile_c + wc * 48 + j * 16 + lrow;
                    conf_out[((size_t)n * L_DIM + row) * S_DIM + col] = conf;
                    unsigned long long p =
                        ((unsigned long long)__float_as_uint(conf) << 32) | (unsigned)col;
                    if (p > rmax[i][q]) rmax[i][q] = p;
                    if (conf > cmax[j]) cmax[j] = conf;
                }

        #pragma unroll
        for (int m = 1; m < 16; m <<= 1)
            #pragma unroll
            for (int i = 0; i < 6; ++i)
                #pragma unroll
                for (int q = 0; q < 4; ++q) {
                    unsigned long long o = __shfl_xor(rmax[i][q], m, 64);
                    if (o > rmax[i][q]) rmax[i][q] = o;
                }
        if (lrow == 0) {
            #pragma unroll
            for (int i = 0; i < 6; ++i)
                #pragma unroll
                for (int q = 0; q < 4; ++q)
                    atomicMax(&rowarg[(size_t)n * L_DIM + tile_r + wr * 96 + i * 16 + kgrp * 4 + q],
                              rmax[i][q]);
        }
        #pragma unroll
        for (int m = 16; m < 64; m <<= 1)
            #pragma unroll
            for (int j = 0; j < 3; ++j) {
                float o = __shfl_xor(cmax[j], m, 64);
                if (o > cmax[j]) cmax[j] = o;
            }
        if (kgrp == 0) {
            #pragma unroll
            for (int j = 0; j < 3; ++j)
                atomicMax(&colmaxbits[(size_t)n * S_DIM + tile_c + wc * 48 + j * 16 + lrow],
                          __float_as_uint(cmax[j]));
        }
    }
}

// ---- K3: match extraction ---------------------------------------------------
__global__ __launch_bounds__(256)
void finalize_kernel(const unsigned long long* __restrict__ rowarg,
                     const unsigned int* __restrict__ colmaxbits,
                     float* __restrict__ out_maskv,
                     float* __restrict__ out_allj,
                     float* __restrict__ out_mconf) {
    int idx = blockIdx.x * 256 + threadIdx.x;
    if (idx >= N_B * L_DIM) return;
    int n = idx / L_DIM;
    int l = idx - n * L_DIM;
    unsigned long long p = rowarg[idx];
    unsigned int cbits = (unsigned int)(p >> 32);
    int s = (int)(p & 0xffffffffu);
    float cv = __uint_as_float(cbits);
    int i0 = l / W0, j0 = l - i0 * W0;
    int i1 = s / W1, j1 = s - i1 * W1;
    bool border = (i0 >= BORDER) && (i0 < H0 - BORDER) &&
                  (j0 >= BORDER) && (j0 < W0 - BORDER) &&
                  (i1 >= BORDER) && (i1 < H1 - BORDER) &&
                  (j1 >= BORDER) && (j1 < W1 - BORDER);
    bool matched = (cv > THR) && border && (colmaxbits[n * S_DIM + s] == cbits);
    out_maskv[idx] = matched ? 1.0f : 0.0f;
    out_allj[idx]  = matched ? (float)s : 0.0f;
    out_mconf[idx] = matched ? cv : 0.0f;
}

extern "C" void kernel_launch(void* const* d_in, const int* in_sizes, int n_in,
                              void* d_out, int out_size, void* d_ws, size_t ws_size,
                              hipStream_t stream) {
    const float* f0 = (const float*)d_in[0];
    const float* f1 = (const float*)d_in[1];
    float* out = (float*)d_out;

    char* ws = (char*)d_ws;
    unsigned short*     Abf        = (unsigned short*)(ws + OFF_A);
    unsigned short*     Bbf        = (unsigned short*)(ws + OFF_B);
    float*              rowsum     = (float*)(ws + OFF_RS);
    float*              colsum     = (float*)(ws + OFF_CS);
    unsigned int*       colmaxbits = (unsigned int*)(ws + OFF_CM);
    unsigned long long* rowarg     = (unsigned long long*)(ws + OFF_RA);

    hipMemsetAsync(ws + OFF_RS, 0, ZERO_BYTES, stream);

    convert_kernel<<<2400, 256, 0, stream>>>(f0, f1, Abf, Bbf);

    dim3 grid(S_DIM / TILE, L_DIM / TILE, N_B);   // 25 x 25 x 2
    gemm_pass<1><<<grid, 512, 0, stream>>>(Abf, Bbf, rowsum, colsum,
                                           nullptr, nullptr, nullptr);
    gemm_pass<2><<<grid, 512, 0, stream>>>(Abf, Bbf, rowsum, colsum,
                                           rowarg, colmaxbits, out);

    const size_t CONF_ELEMS = (size_t)N_B * L_DIM * S_DIM;
    float* out_maskv = out + CONF_ELEMS;
    float* out_allj  = out_maskv + (size_t)N_B * L_DIM;
    float* out_mconf = out_allj  + (size_t)N_B * L_DIM;
    finalize_kernel<<<(N_B * L_DIM + 255) / 256, 256, 0, stream>>>(
        rowarg, colmaxbits, out_maskv, out_allj, out_mconf);
}